// Round 1
// baseline (474.138 us; speedup 1.0000x reference)
//
#include <hip/hip_runtime.h>
#include <math.h>

// Problem: opening = erode(10x10 flat, SAME) then dilate(10x10 flat, SAME), x1.0
// NHWC fp32 [16,512,512,8]. SAME pad for k=10: lo=4, hi=5 -> window [i-4, i+5].
// Separable: 4 one-D passes (minW, minH, maxW, maxH).
// Each thread: one float4 (4 channels) x run of 8 outputs along pass dir.
// 17 taps -> prefix/suffix sliding min/max (all 8 windows contain tap index 8).

#define N_ 16
#define H_ 512
#define W_ 512
#define ROW_F4 1024              // W_ * C/4 = 512*2
#define IMG_F4 (H_ * ROW_F4)     // 524288

__device__ __forceinline__ float4 f4min(float4 a, float4 b) {
    return make_float4(fminf(a.x,b.x), fminf(a.y,b.y), fminf(a.z,b.z), fminf(a.w,b.w));
}
__device__ __forceinline__ float4 f4max(float4 a, float4 b) {
    return make_float4(fmaxf(a.x,b.x), fmaxf(a.y,b.y), fmaxf(a.z,b.z), fmaxf(a.w,b.w));
}

template <bool IS_MIN>
__device__ __forceinline__ float4 f4op(float4 a, float4 b) {
    return IS_MIN ? f4min(a, b) : f4max(a, b);
}

// ---- W-direction pass: out[n][h][w][c] = op over in[n][h][w-4 .. w+5][c] ----
// task id t: sub = t & 127 -> c4 = sub&1, wrun = sub>>1 (64 runs of 8 px);
//            row = t >> 7  (n*H + h, 8192 rows). tasks = 8192*128 = 1,048,576.
template <bool IS_MIN>
__global__ __launch_bounds__(256) void pass_w(const float4* __restrict__ in,
                                              float4* __restrict__ out) {
    const float IDENT = IS_MIN ? INFINITY : -INFINITY;
    const float4 ident4 = make_float4(IDENT, IDENT, IDENT, IDENT);

    unsigned t   = blockIdx.x * 256u + threadIdx.x;
    unsigned sub = t & 127u;
    unsigned c4  = sub & 1u;
    int      w0  = (int)((sub >> 1) * 8u);
    unsigned row = t >> 7;

    const float4* rowp = in  + (size_t)row * ROW_F4;
    float4*       orow = out + (size_t)row * ROW_F4;

    float4 v[17];
#pragma unroll
    for (int q = 0; q < 17; q++) {
        int w = w0 + q - 4;
        v[q] = (w >= 0 && w < W_) ? rowp[(size_t)(w * 2 + (int)c4)] : ident4;
    }

    // L[i] = op(v[i..8]); R_i = op(v[9..9+i]); out[i] = op(L[i], R_i), windows i..i+9
    float4 L[9];
    L[8] = v[8];
#pragma unroll
    for (int i = 7; i >= 0; i--) L[i] = f4op<IS_MIN>(v[i], L[i + 1]);

    float4 r = v[9];
#pragma unroll
    for (int i = 0; i < 8; i++) {
        if (i > 0) r = f4op<IS_MIN>(r, v[9 + i]);
        orow[(size_t)((w0 + i) * 2 + (int)c4)] = f4op<IS_MIN>(L[i], r);
    }
}

// ---- H-direction pass: out[n][h][w][c] = op over in[n][h-4 .. h+5][w][c] ----
// task id t: wc4 = t & 1023 (contiguous W*C/4), hrun = (t>>10)&63, n = t>>16.
// Perfectly coalesced: per tap a wave reads 64 consecutive float4s.
template <bool IS_MIN>
__global__ __launch_bounds__(256) void pass_h(const float4* __restrict__ in,
                                              float4* __restrict__ out) {
    const float IDENT = IS_MIN ? INFINITY : -INFINITY;
    const float4 ident4 = make_float4(IDENT, IDENT, IDENT, IDENT);

    unsigned t   = blockIdx.x * 256u + threadIdx.x;
    unsigned wc4 = t & 1023u;
    int      h0  = (int)(((t >> 10) & 63u) * 8u);
    unsigned n   = t >> 16;

    const float4* img  = in  + (size_t)n * IMG_F4;
    float4*       oimg = out + (size_t)n * IMG_F4;

    float4 v[17];
#pragma unroll
    for (int q = 0; q < 17; q++) {
        int h = h0 + q - 4;
        v[q] = (h >= 0 && h < H_) ? img[(size_t)h * ROW_F4 + wc4] : ident4;
    }

    float4 L[9];
    L[8] = v[8];
#pragma unroll
    for (int i = 7; i >= 0; i--) L[i] = f4op<IS_MIN>(v[i], L[i + 1]);

    float4 r = v[9];
#pragma unroll
    for (int i = 0; i < 8; i++) {
        if (i > 0) r = f4op<IS_MIN>(r, v[9 + i]);
        oimg[(size_t)(h0 + i) * ROW_F4 + wc4] = f4op<IS_MIN>(L[i], r);
    }
}

extern "C" void kernel_launch(void* const* d_in, const int* in_sizes, int n_in,
                              void* d_out, int out_size, void* d_ws, size_t ws_size,
                              hipStream_t stream) {
    const float4* in  = (const float4*)d_in[0];
    float4*       out = (float4*)d_out;
    float4*       ws  = (float4*)d_ws;   // needs 128 MiB; ping-pong ws <-> out

    const int blocks = 4096;  // 1,048,576 tasks / 256

    // opening: erosion (min) then dilation (max), each separable W then H
    pass_w<true ><<<blocks, 256, 0, stream>>>(in,  ws);   // minW : in  -> ws
    pass_h<true ><<<blocks, 256, 0, stream>>>(ws,  out);  // minH : ws  -> out (eroded)
    pass_w<false><<<blocks, 256, 0, stream>>>(out, ws);   // maxW : out -> ws
    pass_h<false><<<blocks, 256, 0, stream>>>(ws,  out);  // maxH : ws  -> out (opened)
}

// Round 2
// 472.163 us; speedup vs baseline: 1.0042x; 1.0042x over previous
//
#include <hip/hip_runtime.h>
#include <math.h>

// Morphological opening, 10x10 flat kernel, SAME padding (lo=4, hi=5).
// NHWC fp32 [16,512,512,8], fully fused into ONE kernel:
//   per 32x32-pixel output tile: stage input(+18 halo) to LDS, then
//   minW -> minH(+out-of-image mask to -inf) -> maxW -> maxH in LDS.
// Each stage uses the 17-tap prefix/suffix trick: 8 outputs from 17 taps,
// ~3 min-ops/output. Pixel = 8 ch = 2 float4 ("c4" in {0,1}).

#define W_F4   1024              // 512 px * 2 f4
#define IMG_F4 (512 * W_F4)

#define TH 32
#define TW 32

// LDS geometry (f4 units). Strides padded so (stride mod 8) is odd ->
// row-strided ds_read_b128 across lanes stays at the bank-cycle floor.
#define R_IN 50                  // TH + 18 rows
#define C_IN 100                 // (TW + 18) px * 2
#define S_IN 101
#define R_A  50                  // minW out: 50 rows x 41 px
#define C_A  82
#define S_A  83
#define R_E  41                  // eroded: 41 rows x 41 px (aliases sIn)
#define S_E  83
#define R_B  41                  // maxW out: 41 rows x 32 px (aliases sA)
#define S_B  65

__device__ __forceinline__ float4 f4min(float4 a, float4 b) {
    return make_float4(fminf(a.x,b.x), fminf(a.y,b.y), fminf(a.z,b.z), fminf(a.w,b.w));
}
__device__ __forceinline__ float4 f4max(float4 a, float4 b) {
    return make_float4(fmaxf(a.x,b.x), fmaxf(a.y,b.y), fmaxf(a.z,b.z), fmaxf(a.w,b.w));
}

__global__ __launch_bounds__(256) void opening_fused(const float4* __restrict__ in,
                                                     float4* __restrict__ out) {
    __shared__ float4 sIn[R_IN * S_IN];   // 5050 f4 = 80.8 KB
    __shared__ float4 sA [R_A  * S_A ];   // 4150 f4 = 66.4 KB

    const int t  = threadIdx.x;
    const int tw = blockIdx.x, th = blockIdx.y, n = blockIdx.z;
    const int h0 = th * TH, w0 = tw * TW;           // output tile origin (px)

    const float4* img  = in  + (size_t)n * IMG_F4;
    float4*       oimg = out + (size_t)n * IMG_F4;

    const float4 PINF4 = make_float4( INFINITY,  INFINITY,  INFINITY,  INFINITY);
    const float4 NINF4 = make_float4(-INFINITY, -INFINITY, -INFINITY, -INFINITY);

    // ---- stage 1: global -> sIn (coalesced; pad slots & OOB get +inf) ----
    for (int idx = t; idx < R_IN * S_IN; idx += 256) {
        int r  = idx / S_IN;
        int c  = idx - r * S_IN;
        int h  = h0 - 8 + r;
        int wf = w0 * 2 - 16 + c;                   // f4 column
        float4 v = PINF4;
        if (c < C_IN && h >= 0 && h < 512 && wf >= 0 && wf < W_F4)
            v = img[(size_t)h * W_F4 + wf];
        sIn[idx] = v;
    }
    __syncthreads();

    // ---- stage 2: minW  sIn -> sA.  A(r, j) = min in px j..j+9.  600 runs ----
    for (int rho = t; rho < 600; rho += 256) {
        int r    = rho % 50;
        int rest = rho / 50;
        int c4   = rest & 1;
        int p    = rest >> 1;                       // run of 8 A-pixels
        float4 v[17];
#pragma unroll
        for (int q = 0; q < 17; q++) {
            int px = p * 8 + q;
            v[q] = (px < 50) ? sIn[r * S_IN + px * 2 + c4] : PINF4;
        }
        float4 L[9]; L[8] = v[8];
#pragma unroll
        for (int i = 7; i >= 0; i--) L[i] = f4min(v[i], L[i + 1]);
        float4 rr = v[9];
#pragma unroll
        for (int i = 0; i < 8; i++) {
            if (i > 0) rr = f4min(rr, v[9 + i]);
            int j = p * 8 + i;
            if (j < 41) sA[r * S_A + j * 2 + c4] = f4min(L[i], rr);
        }
    }
    __syncthreads();

    // ---- stage 3: minH  sA -> sE (alias sIn), mask out-of-image -> -inf ----
    float4* sE = sIn;
    for (int rho = t; rho < 492; rho += 256) {      // 82 cols x 6 row-runs
        int c = rho % 82;
        int p = rho / 82;
        float4 v[17];
#pragma unroll
        for (int q = 0; q < 17; q++) {
            int a = p * 8 + q;
            v[q] = (a < 50) ? sA[a * S_A + c] : PINF4;
        }
        float4 L[9]; L[8] = v[8];
#pragma unroll
        for (int i = 7; i >= 0; i--) L[i] = f4min(v[i], L[i + 1]);
        float4 rr = v[9];
        int wpx = w0 - 4 + (c >> 1);                // absolute w of this eroded col
        bool win = (wpx >= 0 && wpx < 512);
#pragma unroll
        for (int i = 0; i < 8; i++) {
            if (i > 0) rr = f4min(rr, v[9 + i]);
            int i2 = p * 8 + i;
            if (i2 < 41) {
                int h = h0 - 4 + i2;                // absolute h of this eroded row
                bool inside = win && (h >= 0 && h < 512);
                sE[i2 * S_E + c] = inside ? f4min(L[i], rr) : NINF4;
            }
        }
    }
    __syncthreads();

    // ---- stage 4: maxW  sE -> sB (alias sA).  B(r, j) = max eroded px j..j+9 ----
    float4* sB = sA;
    for (int rho = t; rho < 328; rho += 256) {      // 41 rows x 2 c4 x 4 runs
        int r    = rho % 41;
        int rest = rho / 41;
        int c4   = rest & 1;
        int p    = rest >> 1;
        float4 v[17];
#pragma unroll
        for (int q = 0; q < 17; q++)
            v[q] = sE[r * S_E + (p * 8 + q) * 2 + c4];   // px <= 40, in range
        float4 L[9]; L[8] = v[8];
#pragma unroll
        for (int i = 7; i >= 0; i--) L[i] = f4max(v[i], L[i + 1]);
        float4 rr = v[9];
#pragma unroll
        for (int i = 0; i < 8; i++) {
            if (i > 0) rr = f4max(rr, v[9 + i]);
            sB[r * S_B + (p * 8 + i) * 2 + c4] = f4max(L[i], rr);
        }
    }
    __syncthreads();

    // ---- stage 5: maxH  sB -> global (coalesced).  256 runs, 1/thread ----
    {
        int c = t & 63;                             // f4 col within tile
        int p = t >> 6;                             // run of 8 output rows
        float4 v[17];
#pragma unroll
        for (int q = 0; q < 17; q++)
            v[q] = sB[(p * 8 + q) * S_B + c];       // rows <= 40, in range
        float4 L[9]; L[8] = v[8];
#pragma unroll
        for (int i = 7; i >= 0; i--) L[i] = f4max(v[i], L[i + 1]);
        float4 rr = v[9];
#pragma unroll
        for (int i = 0; i < 8; i++) {
            if (i > 0) rr = f4max(rr, v[9 + i]);
            oimg[(size_t)(h0 + p * 8 + i) * W_F4 + w0 * 2 + c] = f4max(L[i], rr);
        }
    }
}

extern "C" void kernel_launch(void* const* d_in, const int* in_sizes, int n_in,
                              void* d_out, int out_size, void* d_ws, size_t ws_size,
                              hipStream_t stream) {
    const float4* in  = (const float4*)d_in[0];
    float4*       out = (float4*)d_out;

    dim3 grid(16, 16, 16);   // (tw, th, n): 512/32 = 16 tiles per dim, 16 images
    opening_fused<<<grid, 256, 0, stream>>>(in, out);
}